// Round 17
// baseline (834.666 us; speedup 1.0000x reference)
//
#include <hip/hip_runtime.h>
#include <hip/hip_bf16.h>

typedef __attribute__((ext_vector_type(4))) int int4v;

#define MFMA_I8(a, b, c) __builtin_amdgcn_mfma_i32_16x16x64_i8((a), (b), (c), 0, 0, 0)
#define GLDS16(g, l)                                                                        \
  __builtin_amdgcn_global_load_lds((const __attribute__((address_space(1))) void*)(g),      \
                                   (__attribute__((address_space(3))) void*)(l), 16, 0, 0)
#define SBAR() __builtin_amdgcn_s_barrier()
#define SCHED0() __builtin_amdgcn_sched_barrier(0)

static constexpr int NTOK = 4096;
static constexpr int DDIM = 4096;
static constexpr int FDIM = 11008;

// ---------------------------------------------------------------- utilities

__device__ __forceinline__ float wave_max64(float m) {
#pragma unroll
  for (int o = 32; o > 0; o >>= 1) m = fmaxf(m, __shfl_xor(m, o));
  return m;
}

// ---- balanced absmax over 4 unequal tensors: 1-D grid, work-proportional
// block split (x:64MB, w:180MB each). c0=226, then 608 per w (2050 blocks).
__global__ void absmax_bal(const float* x, const float* w1, const float* w3, const float* w2,
                           unsigned* slots, int n4x, int n4w) {
  const int b = blockIdx.x;
  int seg, lb, nb;
  if (b < 226) {
    seg = 0; lb = b; nb = 226;
  } else if (b < 834) {
    seg = 1; lb = b - 226; nb = 608;
  } else if (b < 1442) {
    seg = 2; lb = b - 834; nb = 608;
  } else {
    seg = 3; lb = b - 1442; nb = 608;
  }
  const float* p = (seg == 0) ? x : (seg == 1) ? w1 : (seg == 2) ? w3 : w2;
  const int n4 = (seg == 0) ? n4x : n4w;

  float m = 0.f;
  const int stride = nb * blockDim.x;
  for (int i = lb * blockDim.x + threadIdx.x; i < n4; i += stride) {
    float4 v = reinterpret_cast<const float4*>(p)[i];
    m = fmaxf(fmaxf(fabsf(v.x), fabsf(v.y)), fmaxf(fmaxf(fabsf(v.z), fabsf(v.w)), m));
  }
  m = wave_max64(m);
  __shared__ float wm[4];
  const int lane = threadIdx.x & 63, w = threadIdx.x >> 6;
  if (lane == 0) wm[w] = m;
  __syncthreads();
  if (threadIdx.x == 0) {
    m = fmaxf(fmaxf(wm[0], wm[1]), fmaxf(wm[2], wm[3]));
    atomicMax(slots + seg, __float_as_uint(m));
  }
}

__device__ __forceinline__ void quant_range(const float* __restrict__ in,
                                            unsigned* __restrict__ out, int n4,
                                            const unsigned* __restrict__ slot,
                                            int lb, int nb) {
  const float s = fmaxf(__uint_as_float(*slot), 1e-8f) / 127.0f;
  const int stride = nb * blockDim.x;
  for (int i = lb * blockDim.x + threadIdx.x; i < n4; i += stride) {
    float4 v = reinterpret_cast<const float4*>(in)[i];
    const int q0 = (int)rintf(v.x / s), q1 = (int)rintf(v.y / s);
    const int q2 = (int)rintf(v.z / s), q3 = (int)rintf(v.w / s);
    out[i] = (unsigned)(q0 & 255) | ((unsigned)(q1 & 255) << 8) |
             ((unsigned)(q2 & 255) << 16) | ((unsigned)(q3 & 255) << 24);
  }
}

// FRAG-MAJOR weight quant (layout verified R10-R16) for the GLU B-operands.
// u32x4 slot u: block = u>>8 (= p*NKT + kt128), fi = (u&255)>>6, l = u&63.
// Holds W[p*32 + (fi&1)*16 + (l&15)][kt128*128 + (fi>>1)*64 + (l>>4)*16..+15].
__device__ __forceinline__ void quantW_frag_range(const float* __restrict__ in,
                                                  int4v* __restrict__ out,
                                                  const unsigned* __restrict__ slot,
                                                  int K, int NKT, int total,
                                                  int lb, int nb) {
  const float s = fmaxf(__uint_as_float(*slot), 1e-8f) / 127.0f;
  const int stride = nb * blockDim.x;
  for (int u = lb * blockDim.x + threadIdx.x; u < total; u += stride) {
    const int block = u >> 8;
    const int sidx = u & 255;
    const int fi = sidx >> 6;
    const int l = sidx & 63;
    const int p = block / NKT;
    const int kt = block - p * NKT;
    const int row = p * 32 + (fi & 1) * 16 + (l & 15);
    const int k0 = kt * 128 + (fi >> 1) * 64 + (l >> 4) * 16;
    const float4* src = reinterpret_cast<const float4*>(in + (size_t)row * K + k0);
    unsigned r[4];
#pragma unroll
    for (int j = 0; j < 4; ++j) {
      float4 v = src[j];
      const int q0 = (int)rintf(v.x / s), q1 = (int)rintf(v.y / s);
      const int q2 = (int)rintf(v.z / s), q3 = (int)rintf(v.w / s);
      r[j] = (unsigned)(q0 & 255) | ((unsigned)(q1 & 255) << 8) |
             ((unsigned)(q2 & 255) << 16) | ((unsigned)(q3 & 255) << 24);
    }
    out[u] = (int4v){(int)r[0], (int)r[1], (int)r[2], (int)r[3]};
  }
}

// balanced quant: c0=452, 1215 per w (4097 blocks)
__global__ void quant_bal(const float* x, const float* w1, const float* w3, const float* w2,
                          unsigned* qx, unsigned* qw1, unsigned* qw3, unsigned* qw2,
                          const unsigned* slots, int n4x, int n4w) {
  const int b = blockIdx.x;
  const int totW = FDIM * (DDIM / 16);
  int seg, lb, nb;
  if (b < 452) {
    seg = 0; lb = b; nb = 452;
  } else if (b < 1667) {
    seg = 1; lb = b - 452; nb = 1215;
  } else if (b < 2882) {
    seg = 2; lb = b - 1667; nb = 1215;
  } else {
    seg = 3; lb = b - 2882; nb = 1215;
  }
  if (seg == 0) quant_range(x, qx, n4x, slots + 0, lb, nb);
  else if (seg == 1) quantW_frag_range(w1, (int4v*)qw1, slots + 1, DDIM, DDIM / 128, totW, lb, nb);
  else if (seg == 2) quantW_frag_range(w3, (int4v*)qw3, slots + 2, DDIM, DDIM / 128, totW, lb, nb);
  else quant_range(w2, qw2, n4w, slots + 3, lb, nb);  // LINEAR (down consumes row-major)
}

__global__ void quant_kernel(const float* __restrict__ in, unsigned* __restrict__ out,
                             int n4, const unsigned* __restrict__ slot) {
  quant_range(in, out, n4, slot, blockIdx.x, gridDim.x);
}

// ------ fused gate+up GLU GEMM, BK=256 with conflict-free panel layout.
// (R16 measured: 369 us, MfmaUtil 46, conflicts 0 — unchanged this round.)
// Tile 128x128, 4 waves 1M x 4N, per-wave 128r x 32c dual-tensor.
// A in 2 x 32 KB LDS buffers; each buffer = TWO [128][128B] panels,
// stride-128B / XOR-(row&7) swizzle. B in regs: 4 kk-slices resident,
// reloaded per-cluster from frag-major qw. 2 blocks/CU. Boundary: vmcnt(16).
__global__ __launch_bounds__(256, 2) void gemm_glu(
    const signed char* __restrict__ Aq, const signed char* __restrict__ B3f,
    const signed char* __restrict__ B1f, float* __restrict__ H,
    const unsigned* __restrict__ slots, unsigned* __restrict__ hslot) {
  constexpr int K = DDIM;
  constexpr int NT = K >> 8;   // 16 tiles of BK=256
  __shared__ char lds[65536];  // 2 bufs x (2 panels x 16 KB)

  const int t = threadIdx.x;
  const int l = t & 63;
  const int w = t >> 6;  // 0..3

  const int gx = gridDim.x, gy = gridDim.y;
  const int nwg = gx * gy;
  const int i0 = blockIdx.y * gx + blockIdx.x;
  const int cid = (i0 & 7) * (nwg >> 3) + (i0 >> 3);
  const int rowA0 = (cid % gy) << 7;
  const int colB0 = (cid / gy) << 7;

  const int rlA = t >> 3;
  const int glA = (t & 7) ^ (rlA & 7);
  const signed char* aP = Aq + (size_t)(rowA0 + rlA) * K + glA * 16;
  const size_t r32 = (size_t)32 * K;
  const int stW = w * 1024;

  const int p0 = (colB0 >> 5) + w;
  const signed char* w3b = B3f + (size_t)p0 * 32 * 4096 + l * 16;
  const signed char* w1b = B1f + (size_t)p0 * 32 * 4096 + l * 16;

#define STAGE_A(KT, BUF)                                                 \
  do {                                                                   \
    const size_t kO_ = (size_t)(KT) * 256;                               \
    GLDS16(aP + kO_, &lds[(BUF) + stW]);                                 \
    GLDS16(aP + r32 + kO_, &lds[(BUF) + 4096 + stW]);                    \
    GLDS16(aP + 2 * r32 + kO_, &lds[(BUF) + 8192 + stW]);                \
    GLDS16(aP + 3 * r32 + kO_, &lds[(BUF) + 12288 + stW]);               \
    GLDS16(aP + kO_ + 128, &lds[(BUF) + 16384 + stW]);                   \
    GLDS16(aP + r32 + kO_ + 128, &lds[(BUF) + 16384 + 4096 + stW]);      \
    GLDS16(aP + 2 * r32 + kO_ + 128, &lds[(BUF) + 16384 + 8192 + stW]);  \
    GLDS16(aP + 3 * r32 + kO_ + 128, &lds[(BUF) + 16384 + 12288 + stW]); \
  } while (0)

#define LDSF(BASE, R, G)                                                      \
  (*reinterpret_cast<const int4v*>(                                           \
      &lds[(BASE) + (R)*128 + (((G) ^ ((R)&7)) << 4)]))

  int4v acc3[8][2], acc1[8][2];
#pragma unroll
  for (int m = 0; m < 8; ++m)
#pragma unroll
    for (int n = 0; n < 2; ++n) {
      acc3[m][n] = (int4v){0, 0, 0, 0};
      acc1[m][n] = (int4v){0, 0, 0, 0};
    }

  const int lr = l & 15;
  const int cr = l >> 4;

  int4v b3s[4][2], b1s[4][2];

  STAGE_A(0, 0);
#pragma unroll
  for (int kk = 0; kk < 4; ++kk) {
    const size_t o_ = (size_t)(kk >> 1) * 4096 + (size_t)(kk & 1) * 2048;
    b3s[kk][0] = *(const int4v*)(w3b + o_);
    b3s[kk][1] = *(const int4v*)(w3b + o_ + 1024);
    b1s[kk][0] = *(const int4v*)(w1b + o_);
    b1s[kk][1] = *(const int4v*)(w1b + o_ + 1024);
  }

  for (int kt = 0; kt < NT; ++kt) {
    const int rb = (kt & 1) * 32768;
    const bool nx = (kt + 1 < NT);

    SCHED0();
    if (nx) {
      asm volatile("s_waitcnt vmcnt(16)" ::: "memory");
    } else {
      asm volatile("s_waitcnt vmcnt(0)" ::: "memory");
    }
    SBAR();
    SCHED0();

    if (nx) STAGE_A(kt + 1, rb ^ 32768);

#pragma unroll
    for (int kk = 0; kk < 4; ++kk) {
      const int pb = rb + (kk >> 1) * 16384;  // panel base
      const int Gb = (kk & 1) * 4 + cr;       // granule within panel
#pragma unroll
      for (int mh = 0; mh < 2; ++mh) {
        int4v a_[4];
#pragma unroll
        for (int m = 0; m < 4; ++m) a_[m] = LDSF(pb, (mh * 4 + m) * 16 + lr, Gb);
        __builtin_amdgcn_s_setprio(1);
#pragma unroll
        for (int m = 0; m < 4; ++m) {
          const int mi = mh * 4 + m;
          acc3[mi][0] = MFMA_I8(a_[m], b3s[kk][0], acc3[mi][0]);
          acc3[mi][1] = MFMA_I8(a_[m], b3s[kk][1], acc3[mi][1]);
          acc1[mi][0] = MFMA_I8(a_[m], b1s[kk][0], acc1[mi][0]);
          acc1[mi][1] = MFMA_I8(a_[m], b1s[kk][1], acc1[mi][1]);
        }
        __builtin_amdgcn_s_setprio(0);
      }
      if (nx) {
        const size_t o_ = (size_t)(2 * (kt + 1) + (kk >> 1)) * 4096 +
                          (size_t)(kk & 1) * 2048;
        b3s[kk][0] = *(const int4v*)(w3b + o_);
        b3s[kk][1] = *(const int4v*)(w3b + o_ + 1024);
        b1s[kk][0] = *(const int4v*)(w1b + o_);
        b1s[kk][1] = *(const int4v*)(w1b + o_ + 1024);
      }
    }
  }

  // ------------------------------------------------------------- epilogue
  const float sx = fmaxf(__uint_as_float(slots[0]), 1e-8f) / 127.0f;
  const float sw1 = fmaxf(__uint_as_float(slots[1]), 1e-8f) / 127.0f;
  const float sw3 = fmaxf(__uint_as_float(slots[2]), 1e-8f) / 127.0f;
  const float s3 = sx * sw3, s1 = sx * sw1;
  const int crow0 = rowA0 + ((l >> 4) << 2);
  const int ccol0 = colB0 + w * 32 + lr;
  float hmax = 0.f;
#pragma unroll
  for (int m = 0; m < 8; ++m)
#pragma unroll
    for (int n = 0; n < 2; ++n)
#pragma unroll
      for (int j = 0; j < 4; ++j) {
        const int row = crow0 + m * 16 + j;
        const int col = ccol0 + n * 16;
        const float g = (float)acc3[m][n][j] * s3;
        const float gate = g / (1.f + expf(-g));  // silu
        const float h = (float)acc1[m][n][j] * s1 * gate;
        H[(size_t)row * FDIM + col] = h;
        hmax = fmaxf(hmax, fabsf(h));
      }
  hmax = wave_max64(hmax);
  if (l == 0) atomicMax(hslot, __float_as_uint(hmax));
#undef STAGE_A
#undef LDSF
}

// ------- 256x256 down GEMM (measured-best), BK=128, 1 barrier/tile.
// Only change this round: nontemporal store for `out` (never re-read).
__global__ __launch_bounds__(512, 2) void gemm_down(
    const signed char* __restrict__ Aq, const signed char* __restrict__ Bq,
    float* __restrict__ C, const unsigned* __restrict__ slots, int sA, int sB,
    int K, int ldc) {
  __shared__ char lds[131072];  // 2 x 65536

  const int t = threadIdx.x;
  const int l = t & 63;
  const int w = t >> 6;
  const int wm = w >> 2;  // 0..1
  const int wn = w & 3;   // 0..3

  const int gx = gridDim.x, gy = gridDim.y;
  const int nwg = gx * gy;
  const int i0 = blockIdx.y * gx + blockIdx.x;
  const int cid = (i0 & 7) * (nwg >> 3) + (i0 >> 3);
  const int rowA0 = (cid % gy) << 8;
  const int colB0 = (cid / gy) << 8;

  const int rl = t >> 3;
  const int gl = (t & 7) ^ (rl & 7);
  const signed char* aP = Aq + (size_t)(rowA0 + rl) * K + gl * 16;
  const signed char* bP = Bq + (size_t)(colB0 + rl) * K + gl * 16;
  const size_t r64 = (size_t)64 * K;
  const int stW = w * 1024;

#define STAGE8(KO, BASE)                                             \
  do {                                                               \
    GLDS16(aP + (KO), &lds[(BASE) + stW]);                           \
    GLDS16(aP + r64 + (KO), &lds[(BASE) + 8192 + stW]);              \
    GLDS16(aP + 2 * r64 + (KO), &lds[(BASE) + 16384 + stW]);         \
    GLDS16(aP + 3 * r64 + (KO), &lds[(BASE) + 24576 + stW]);         \
    GLDS16(bP + (KO), &lds[(BASE) + 32768 + stW]);                   \
    GLDS16(bP + r64 + (KO), &lds[(BASE) + 40960 + stW]);             \
    GLDS16(bP + 2 * r64 + (KO), &lds[(BASE) + 49152 + stW]);         \
    GLDS16(bP + 3 * r64 + (KO), &lds[(BASE) + 57344 + stW]);         \
  } while (0)

#define LDSF(BASE, ROW, G)                                                    \
  (*reinterpret_cast<const int4v*>(                                           \
      &lds[(BASE) + (ROW)*128 + (((G) ^ ((ROW)&7)) << 4)]))

  int4v acc[8][4];
#pragma unroll
  for (int m = 0; m < 8; ++m)
#pragma unroll
    for (int n = 0; n < 4; ++n) acc[m][n] = (int4v){0, 0, 0, 0};

  const int NT = K >> 7;  // 86
  const int arow = wm * 128 + (l & 15);
  const int brow = wn * 64 + (l & 15);
  const int cr = l >> 4;

  STAGE8(0, 0);

  for (int kt = 0; kt < NT; ++kt) {
    const int rb = (kt & 1) * 65536;
    SCHED0();
    asm volatile("s_waitcnt vmcnt(0)" ::: "memory");
    SBAR();
    SCHED0();

    if (kt + 1 < NT) STAGE8((size_t)(kt + 1) * 128, rb ^ 65536);

#pragma unroll
    for (int kk = 0; kk < 2; ++kk) {
      int4v a[8], b[4];
#pragma unroll
      for (int m = 0; m < 8; ++m) a[m] = LDSF(rb, arow + m * 16, kk * 4 + cr);
#pragma unroll
      for (int n = 0; n < 4; ++n) b[n] = LDSF(rb + 32768, brow + n * 16, kk * 4 + cr);
      __builtin_amdgcn_s_setprio(1);
#pragma unroll
      for (int m = 0; m < 8; ++m)
#pragma unroll
        for (int n = 0; n < 4; ++n) acc[m][n] = MFMA_I8(a[m], b[n], acc[m][n]);
      __builtin_amdgcn_s_setprio(0);
    }
  }

  const float sa = fmaxf(__uint_as_float(slots[sA]), 1e-8f) / 127.0f;
  const float sb2 = fmaxf(__uint_as_float(slots[sB]), 1e-8f) / 127.0f;
  const float s = sa * sb2;
  const int crow0 = rowA0 + wm * 128 + ((l >> 4) << 2);
  const int ccol0 = colB0 + wn * 64 + (l & 15);
#pragma unroll
  for (int m = 0; m < 8; ++m)
#pragma unroll
    for (int n = 0; n < 4; ++n)
#pragma unroll
      for (int j = 0; j < 4; ++j) {
        const int row = crow0 + m * 16 + j;
        const int col = ccol0 + n * 16;
        __builtin_nontemporal_store((float)acc[m][n][j] * s, &C[(size_t)row * ldc + col]);
      }
#undef STAGE8
#undef LDSF
}

// ------------------------------------------------------------------- launch

extern "C" void kernel_launch(void* const* d_in, const int* in_sizes, int n_in,
                              void* d_out, int out_size, void* d_ws, size_t ws_size,
                              hipStream_t stream) {
  const float* x = (const float*)d_in[0];
  const float* w1 = (const float*)d_in[1];
  const float* w3 = (const float*)d_in[2];
  const float* w2 = (const float*)d_in[3];
  float* out = (float*)d_out;
  char* ws = (char*)d_ws;

  unsigned* slots = (unsigned*)ws;  // [0]=x [1]=w1 [2]=w3 [3]=w2 [4]=h absmax
  size_t off = 256;
  signed char* qx = (signed char*)(ws + off);
  off += (size_t)NTOK * DDIM;
  signed char* qw3 = (signed char*)(ws + off);  // frag-major (NKT=32)
  off += (size_t)FDIM * DDIM;
  signed char* qw1 = (signed char*)(ws + off);  // frag-major (NKT=32)
  off += (size_t)FDIM * DDIM;
  signed char* qw2 = (signed char*)(ws + off);  // linear row-major
  off += (size_t)FDIM * DDIM;
  float* H = (float*)(ws + off);
  off += (size_t)NTOK * FDIM * 4;
  signed char* qh = (signed char*)(ws + off);
  off += (size_t)NTOK * FDIM;  // ~385 MB total

  const int n4x = NTOK * DDIM / 4;
  const int n4w = FDIM * DDIM / 4;
  const int n4h = NTOK * FDIM / 4;

  hipMemsetAsync(slots, 0, 64, stream);
  absmax_bal<<<2050, 256, 0, stream>>>(x, w1, w3, w2, slots, n4x, n4w);
  quant_bal<<<4097, 256, 0, stream>>>(x, w1, w3, w2, (unsigned*)qx, (unsigned*)qw1,
                                      (unsigned*)qw3, (unsigned*)qw2, slots, n4x, n4w);

  // fused gate+up: H = (x.w1^T*s1) * silu(x.w3^T*s3), + absmax(H)
  const dim3 gGlu(FDIM / 128, NTOK / 128);  // 86 x 32 = 2752 wgs (%8==0)
  gemm_glu<<<gGlu, 256, 0, stream>>>(qx, qw3, qw1, H, slots, slots + 4);
  quant_kernel<<<2048, 256, 0, stream>>>(H, (unsigned*)qh, n4h, slots + 4);
  // down: out = (h.w2^T) * s
  const dim3 gDn(DDIM / 256, NTOK / 256);  // 16 x 16 = 256 wgs (%8==0)
  gemm_down<<<gDn, 512, 0, stream>>>(qh, qw2, out, slots, 4, 3, FDIM, DDIM);
}

// Round 18
// 813.809 us; speedup vs baseline: 1.0256x; 1.0256x over previous
//
#include <hip/hip_runtime.h>
#include <hip/hip_bf16.h>

typedef __attribute__((ext_vector_type(4))) int int4v;

#define MFMA_I8(a, b, c) __builtin_amdgcn_mfma_i32_16x16x64_i8((a), (b), (c), 0, 0, 0)
#define GLDS16(g, l)                                                                        \
  __builtin_amdgcn_global_load_lds((const __attribute__((address_space(1))) void*)(g),      \
                                   (__attribute__((address_space(3))) void*)(l), 16, 0, 0)
#define SBAR() __builtin_amdgcn_s_barrier()
#define SCHED0() __builtin_amdgcn_sched_barrier(0)

static constexpr int NTOK = 4096;
static constexpr int DDIM = 4096;
static constexpr int FDIM = 11008;

// ---------------------------------------------------------------- utilities

__device__ __forceinline__ float wave_max64(float m) {
#pragma unroll
  for (int o = 32; o > 0; o >>= 1) m = fmaxf(m, __shfl_xor(m, o));
  return m;
}

__device__ __forceinline__ void absmax_body(const float* __restrict__ p, int n4,
                                            unsigned* __restrict__ slot) {
  float m = 0.f;
  const int stride = gridDim.x * blockDim.x;
  for (int i = blockIdx.x * blockDim.x + threadIdx.x; i < n4; i += stride) {
    float4 v = reinterpret_cast<const float4*>(p)[i];
    m = fmaxf(fmaxf(fabsf(v.x), fabsf(v.y)), fmaxf(fmaxf(fabsf(v.z), fabsf(v.w)), m));
  }
  m = wave_max64(m);
  __shared__ float wm[4];
  const int lane = threadIdx.x & 63, w = threadIdx.x >> 6;
  if (lane == 0) wm[w] = m;
  __syncthreads();
  if (threadIdx.x == 0) {
    m = fmaxf(fmaxf(wm[0], wm[1]), fmaxf(wm[2], wm[3]));
    atomicMax(slot, __float_as_uint(m));
  }
}

__global__ void absmax4(const float* x, const float* w1, const float* w3, const float* w2,
                        unsigned* slots, int n4x, int n4w) {
  const int seg = blockIdx.y;
  const float* p = (seg == 0) ? x : (seg == 1) ? w1 : (seg == 2) ? w3 : w2;
  absmax_body(p, seg == 0 ? n4x : n4w, slots + seg);
}

__device__ __forceinline__ void quant_body(const float* __restrict__ in,
                                           unsigned* __restrict__ out, int n4,
                                           const unsigned* __restrict__ slot) {
  const float s = fmaxf(__uint_as_float(*slot), 1e-8f) / 127.0f;
  const int stride = gridDim.x * blockDim.x;
  for (int i = blockIdx.x * blockDim.x + threadIdx.x; i < n4; i += stride) {
    float4 v = reinterpret_cast<const float4*>(in)[i];
    const int q0 = (int)rintf(v.x / s), q1 = (int)rintf(v.y / s);
    const int q2 = (int)rintf(v.z / s), q3 = (int)rintf(v.w / s);
    out[i] = (unsigned)(q0 & 255) | ((unsigned)(q1 & 255) << 8) |
             ((unsigned)(q2 & 255) << 16) | ((unsigned)(q3 & 255) << 24);
  }
}

// FRAG-MAJOR weight quant (layout verified R10-R16) for the GLU B-operands.
// u32x4 slot u: block = u>>8 (= p*NKT + kt128), fi = (u&255)>>6, l = u&63.
// Holds W[p*32 + (fi&1)*16 + (l&15)][kt128*128 + (fi>>1)*64 + (l>>4)*16..+15].
__device__ __forceinline__ void quantW_frag_body(const float* __restrict__ in,
                                                 int4v* __restrict__ out,
                                                 const unsigned* __restrict__ slot,
                                                 int K, int NKT, int total) {
  const float s = fmaxf(__uint_as_float(*slot), 1e-8f) / 127.0f;
  const int stride = gridDim.x * blockDim.x;
  for (int u = blockIdx.x * blockDim.x + threadIdx.x; u < total; u += stride) {
    const int block = u >> 8;
    const int sidx = u & 255;
    const int fi = sidx >> 6;
    const int l = sidx & 63;
    const int p = block / NKT;
    const int kt = block - p * NKT;
    const int row = p * 32 + (fi & 1) * 16 + (l & 15);
    const int k0 = kt * 128 + (fi >> 1) * 64 + (l >> 4) * 16;
    const float4* src = reinterpret_cast<const float4*>(in + (size_t)row * K + k0);
    unsigned r[4];
#pragma unroll
    for (int j = 0; j < 4; ++j) {
      float4 v = src[j];
      const int q0 = (int)rintf(v.x / s), q1 = (int)rintf(v.y / s);
      const int q2 = (int)rintf(v.z / s), q3 = (int)rintf(v.w / s);
      r[j] = (unsigned)(q0 & 255) | ((unsigned)(q1 & 255) << 8) |
             ((unsigned)(q2 & 255) << 16) | ((unsigned)(q3 & 255) << 24);
    }
    out[u] = (int4v){(int)r[0], (int)r[1], (int)r[2], (int)r[3]};
  }
}

__global__ void quant4(const float* x, const float* w1, const float* w3, const float* w2,
                       unsigned* qx, unsigned* qw1, unsigned* qw3, unsigned* qw2,
                       const unsigned* slots, int n4x, int n4w) {
  const int seg = blockIdx.y;
  const int totW = FDIM * (DDIM / 16);
  if (seg == 0) quant_body(x, qx, n4x, slots + 0);
  else if (seg == 1) quantW_frag_body(w1, (int4v*)qw1, slots + 1, DDIM, DDIM / 128, totW);
  else if (seg == 2) quantW_frag_body(w3, (int4v*)qw3, slots + 2, DDIM, DDIM / 128, totW);
  else quant_body(w2, qw2, n4w, slots + 3);  // LINEAR (down consumes row-major)
}

__global__ void quant_kernel(const float* __restrict__ in, unsigned* __restrict__ out,
                             int n4, const unsigned* __restrict__ slot) {
  quant_body(in, out, n4, slot);
}

// ------ fused gate+up GLU GEMM, BK=256 with conflict-free panel layout.
// (R16 measured: 369 us, MfmaUtil 46.7, bank conflicts 0.)
// Tile 128x128, 4 waves 1M x 4N, per-wave 128r x 32c dual-tensor.
// A in 2 x 32 KB LDS buffers; each buffer = TWO [128][128B] panels
// (panel P = k-range kt*256 + P*128), stride-128B / XOR-(row&7) swizzle.
// B in regs: 4 kk-slices resident (64 VGPR), reloaded per-cluster with
// ~3/4-tile cover from frag-major qw. 2 blocks/CU -> decorrelated barrier
// domains. Boundary: vmcnt(16) drains exactly A(kt+1)'s 8 GLDS.
__global__ __launch_bounds__(256, 2) void gemm_glu(
    const signed char* __restrict__ Aq, const signed char* __restrict__ B3f,
    const signed char* __restrict__ B1f, float* __restrict__ H,
    const unsigned* __restrict__ slots, unsigned* __restrict__ hslot) {
  constexpr int K = DDIM;
  constexpr int NT = K >> 8;   // 16 tiles of BK=256
  __shared__ char lds[65536];  // 2 bufs x (2 panels x 16 KB)

  const int t = threadIdx.x;
  const int l = t & 63;
  const int w = t >> 6;  // 0..3

  // XCD-aware column-major chunking (nwg = 86*32 = 2752, %8==0)
  const int gx = gridDim.x, gy = gridDim.y;
  const int nwg = gx * gy;
  const int i0 = blockIdx.y * gx + blockIdx.x;
  const int cid = (i0 & 7) * (nwg >> 3) + (i0 >> 3);
  const int rowA0 = (cid % gy) << 7;  // 128-row tile
  const int colB0 = (cid / gy) << 7;  // 128-col tile

  // A staging: thread t covers row t>>3 (+32 per instr), 8 granules/panel,
  // pre-swizzled source granule (t&7)^(row&7)
  const int rlA = t >> 3;  // 0..31
  const int glA = (t & 7) ^ (rlA & 7);
  const signed char* aP = Aq + (size_t)(rowA0 + rlA) * K + glA * 16;
  const size_t r32 = (size_t)32 * K;
  const int stW = w * 1024;

  // B bases (frag-major 4 KB blocks of BK=128, block = p*32 + kt128)
  const int p0 = (colB0 >> 5) + w;
  const signed char* w3b = B3f + (size_t)p0 * 32 * 4096 + l * 16;
  const signed char* w1b = B1f + (size_t)p0 * 32 * 4096 + l * 16;

// stage tile KT (BK=256) into buffer BUF: panel0 = k+0..127, panel1 = +128
#define STAGE_A(KT, BUF)                                                 \
  do {                                                                   \
    const size_t kO_ = (size_t)(KT) * 256;                               \
    GLDS16(aP + kO_, &lds[(BUF) + stW]);                                 \
    GLDS16(aP + r32 + kO_, &lds[(BUF) + 4096 + stW]);                    \
    GLDS16(aP + 2 * r32 + kO_, &lds[(BUF) + 8192 + stW]);                \
    GLDS16(aP + 3 * r32 + kO_, &lds[(BUF) + 12288 + stW]);               \
    GLDS16(aP + kO_ + 128, &lds[(BUF) + 16384 + stW]);                   \
    GLDS16(aP + r32 + kO_ + 128, &lds[(BUF) + 16384 + 4096 + stW]);      \
    GLDS16(aP + 2 * r32 + kO_ + 128, &lds[(BUF) + 16384 + 8192 + stW]);  \
    GLDS16(aP + 3 * r32 + kO_ + 128, &lds[(BUF) + 16384 + 12288 + stW]); \
  } while (0)

// swizzled frag read within a panel: row stride 128 B, G = granule 0..7
#define LDSF(BASE, R, G)                                                      \
  (*reinterpret_cast<const int4v*>(                                           \
      &lds[(BASE) + (R)*128 + (((G) ^ ((R)&7)) << 4)]))

  int4v acc3[8][2], acc1[8][2];
#pragma unroll
  for (int m = 0; m < 8; ++m)
#pragma unroll
    for (int n = 0; n < 2; ++n) {
      acc3[m][n] = (int4v){0, 0, 0, 0};
      acc1[m][n] = (int4v){0, 0, 0, 0};
    }

  const int lr = l & 15;
  const int cr = l >> 4;  // 0..3

  // B registers: all 4 kk-slices of the current tile resident
  int4v b3s[4][2], b1s[4][2];

  STAGE_A(0, 0);
#pragma unroll
  for (int kk = 0; kk < 4; ++kk) {
    const size_t o_ = (size_t)(kk >> 1) * 4096 + (size_t)(kk & 1) * 2048;
    b3s[kk][0] = *(const int4v*)(w3b + o_);
    b3s[kk][1] = *(const int4v*)(w3b + o_ + 1024);
    b1s[kk][0] = *(const int4v*)(w1b + o_);
    b1s[kk][1] = *(const int4v*)(w1b + o_ + 1024);
  }

  for (int kt = 0; kt < NT; ++kt) {
    const int rb = (kt & 1) * 32768;
    const bool nx = (kt + 1 < NT);

    // boundary: drain A(kt)'s 8 oldest; B reloads stay in flight
    SCHED0();
    if (nx) {
      asm volatile("s_waitcnt vmcnt(16)" ::: "memory");
    } else {
      asm volatile("s_waitcnt vmcnt(0)" ::: "memory");
    }
    SBAR();
    SCHED0();

    if (nx) STAGE_A(kt + 1, rb ^ 32768);

#pragma unroll
    for (int kk = 0; kk < 4; ++kk) {
      const int pb = rb + (kk >> 1) * 16384;  // panel base
      const int Gb = (kk & 1) * 4 + cr;       // granule within panel
      // two sub-clusters of 4 rows to cap a-frag liveness
#pragma unroll
      for (int mh = 0; mh < 2; ++mh) {
        int4v a_[4];
#pragma unroll
        for (int m = 0; m < 4; ++m) a_[m] = LDSF(pb, (mh * 4 + m) * 16 + lr, Gb);
        __builtin_amdgcn_s_setprio(1);
#pragma unroll
        for (int m = 0; m < 4; ++m) {
          const int mi = mh * 4 + m;
          acc3[mi][0] = MFMA_I8(a_[m], b3s[kk][0], acc3[mi][0]);
          acc3[mi][1] = MFMA_I8(a_[m], b3s[kk][1], acc3[mi][1]);
          acc1[mi][0] = MFMA_I8(a_[m], b1s[kk][0], acc1[mi][0]);
          acc1[mi][1] = MFMA_I8(a_[m], b1s[kk][1], acc1[mi][1]);
        }
        __builtin_amdgcn_s_setprio(0);
      }
      if (nx) {
        const size_t o_ = (size_t)(2 * (kt + 1) + (kk >> 1)) * 4096 +
                          (size_t)(kk & 1) * 2048;
        b3s[kk][0] = *(const int4v*)(w3b + o_);
        b3s[kk][1] = *(const int4v*)(w3b + o_ + 1024);
        b1s[kk][0] = *(const int4v*)(w1b + o_);
        b1s[kk][1] = *(const int4v*)(w1b + o_ + 1024);
      }
    }
  }

  // ------------------------------------------------------------- epilogue
  const float sx = fmaxf(__uint_as_float(slots[0]), 1e-8f) / 127.0f;
  const float sw1 = fmaxf(__uint_as_float(slots[1]), 1e-8f) / 127.0f;
  const float sw3 = fmaxf(__uint_as_float(slots[2]), 1e-8f) / 127.0f;
  const float s3 = sx * sw3, s1 = sx * sw1;
  const int crow0 = rowA0 + ((l >> 4) << 2);
  const int ccol0 = colB0 + w * 32 + lr;
  float hmax = 0.f;
#pragma unroll
  for (int m = 0; m < 8; ++m)
#pragma unroll
    for (int n = 0; n < 2; ++n)
#pragma unroll
      for (int j = 0; j < 4; ++j) {
        const int row = crow0 + m * 16 + j;
        const int col = ccol0 + n * 16;
        const float g = (float)acc3[m][n][j] * s3;
        const float gate = g / (1.f + expf(-g));  // silu
        const float h = (float)acc1[m][n][j] * s1 * gate;
        H[(size_t)row * FDIM + col] = h;
        hmax = fmaxf(hmax, fabsf(h));
      }
  hmax = wave_max64(hmax);
  if (l == 0) atomicMax(hslot, __float_as_uint(hmax));
#undef STAGE_A
#undef LDSF
}

// ------- 256x256 down GEMM (R9/R14 measured-best), BK=128, 1 barrier/tile
__global__ __launch_bounds__(512, 2) void gemm_down(
    const signed char* __restrict__ Aq, const signed char* __restrict__ Bq,
    float* __restrict__ C, const unsigned* __restrict__ slots, int sA, int sB,
    int K, int ldc) {
  __shared__ char lds[131072];  // 2 x 65536

  const int t = threadIdx.x;
  const int l = t & 63;
  const int w = t >> 6;
  const int wm = w >> 2;  // 0..1
  const int wn = w & 3;   // 0..3

  const int gx = gridDim.x, gy = gridDim.y;
  const int nwg = gx * gy;
  const int i0 = blockIdx.y * gx + blockIdx.x;
  const int cid = (i0 & 7) * (nwg >> 3) + (i0 >> 3);
  const int rowA0 = (cid % gy) << 8;
  const int colB0 = (cid / gy) << 8;

  const int rl = t >> 3;
  const int gl = (t & 7) ^ (rl & 7);
  const signed char* aP = Aq + (size_t)(rowA0 + rl) * K + gl * 16;
  const signed char* bP = Bq + (size_t)(colB0 + rl) * K + gl * 16;
  const size_t r64 = (size_t)64 * K;
  const int stW = w * 1024;

#define STAGE8(KO, BASE)                                             \
  do {                                                               \
    GLDS16(aP + (KO), &lds[(BASE) + stW]);                           \
    GLDS16(aP + r64 + (KO), &lds[(BASE) + 8192 + stW]);              \
    GLDS16(aP + 2 * r64 + (KO), &lds[(BASE) + 16384 + stW]);         \
    GLDS16(aP + 3 * r64 + (KO), &lds[(BASE) + 24576 + stW]);         \
    GLDS16(bP + (KO), &lds[(BASE) + 32768 + stW]);                   \
    GLDS16(bP + r64 + (KO), &lds[(BASE) + 40960 + stW]);             \
    GLDS16(bP + 2 * r64 + (KO), &lds[(BASE) + 49152 + stW]);         \
    GLDS16(bP + 3 * r64 + (KO), &lds[(BASE) + 57344 + stW]);         \
  } while (0)

#define LDSF(BASE, ROW, G)                                                    \
  (*reinterpret_cast<const int4v*>(                                           \
      &lds[(BASE) + (ROW)*128 + (((G) ^ ((ROW)&7)) << 4)]))

  int4v acc[8][4];
#pragma unroll
  for (int m = 0; m < 8; ++m)
#pragma unroll
    for (int n = 0; n < 4; ++n) acc[m][n] = (int4v){0, 0, 0, 0};

  const int NT = K >> 7;  // 86
  const int arow = wm * 128 + (l & 15);
  const int brow = wn * 64 + (l & 15);
  const int cr = l >> 4;

  STAGE8(0, 0);

  for (int kt = 0; kt < NT; ++kt) {
    const int rb = (kt & 1) * 65536;
    SCHED0();
    asm volatile("s_waitcnt vmcnt(0)" ::: "memory");
    SBAR();
    SCHED0();

    if (kt + 1 < NT) STAGE8((size_t)(kt + 1) * 128, rb ^ 65536);

#pragma unroll
    for (int kk = 0; kk < 2; ++kk) {
      int4v a[8], b[4];
#pragma unroll
      for (int m = 0; m < 8; ++m) a[m] = LDSF(rb, arow + m * 16, kk * 4 + cr);
#pragma unroll
      for (int n = 0; n < 4; ++n) b[n] = LDSF(rb + 32768, brow + n * 16, kk * 4 + cr);
      __builtin_amdgcn_s_setprio(1);
#pragma unroll
      for (int m = 0; m < 8; ++m)
#pragma unroll
        for (int n = 0; n < 4; ++n) acc[m][n] = MFMA_I8(a[m], b[n], acc[m][n]);
      __builtin_amdgcn_s_setprio(0);
    }
  }

  const float sa = fmaxf(__uint_as_float(slots[sA]), 1e-8f) / 127.0f;
  const float sb2 = fmaxf(__uint_as_float(slots[sB]), 1e-8f) / 127.0f;
  const float s = sa * sb2;
  const int crow0 = rowA0 + wm * 128 + ((l >> 4) << 2);
  const int ccol0 = colB0 + wn * 64 + (l & 15);
#pragma unroll
  for (int m = 0; m < 8; ++m)
#pragma unroll
    for (int n = 0; n < 4; ++n)
#pragma unroll
      for (int j = 0; j < 4; ++j) {
        const int row = crow0 + m * 16 + j;
        const int col = ccol0 + n * 16;
        C[(size_t)row * ldc + col] = (float)acc[m][n][j] * s;
      }
#undef STAGE8
#undef LDSF
}

// ------------------------------------------------------------------- launch

extern "C" void kernel_launch(void* const* d_in, const int* in_sizes, int n_in,
                              void* d_out, int out_size, void* d_ws, size_t ws_size,
                              hipStream_t stream) {
  const float* x = (const float*)d_in[0];
  const float* w1 = (const float*)d_in[1];
  const float* w3 = (const float*)d_in[2];
  const float* w2 = (const float*)d_in[3];
  float* out = (float*)d_out;
  char* ws = (char*)d_ws;

  unsigned* slots = (unsigned*)ws;  // [0]=x [1]=w1 [2]=w3 [3]=w2 [4]=h absmax
  size_t off = 256;
  signed char* qx = (signed char*)(ws + off);
  off += (size_t)NTOK * DDIM;
  signed char* qw3 = (signed char*)(ws + off);  // frag-major (NKT=32)
  off += (size_t)FDIM * DDIM;
  signed char* qw1 = (signed char*)(ws + off);  // frag-major (NKT=32)
  off += (size_t)FDIM * DDIM;
  signed char* qw2 = (signed char*)(ws + off);  // linear row-major
  off += (size_t)FDIM * DDIM;
  float* H = (float*)(ws + off);
  off += (size_t)NTOK * FDIM * 4;
  signed char* qh = (signed char*)(ws + off);
  off += (size_t)NTOK * FDIM;  // ~385 MB total

  const int n4x = NTOK * DDIM / 4;
  const int n4w = FDIM * DDIM / 4;
  const int n4h = NTOK * FDIM / 4;

  hipMemsetAsync(slots, 0, 64, stream);
  absmax4<<<dim3(512, 4), 256, 0, stream>>>(x, w1, w3, w2, slots, n4x, n4w);
  quant4<<<dim3(2048, 4), 256, 0, stream>>>(x, w1, w3, w2, (unsigned*)qx, (unsigned*)qw1,
                                            (unsigned*)qw3, (unsigned*)qw2, slots, n4x, n4w);

  // fused gate+up: H = (x.w1^T*s1) * silu(x.w3^T*s3), + absmax(H)
  const dim3 gGlu(FDIM / 128, NTOK / 128);  // 86 x 32 = 2752 wgs (%8==0)
  gemm_glu<<<gGlu, 256, 0, stream>>>(qx, qw3, qw1, H, slots, slots + 4);
  quant_kernel<<<2048, 256, 0, stream>>>(H, (unsigned*)qh, n4h, slots + 4);
  // down: out = (h.w2^T) * s
  const dim3 gDn(DDIM / 256, NTOK / 256);  // 16 x 16 = 256 wgs (%8==0)
  gemm_down<<<gDn, 512, 0, stream>>>(qh, qw2, out, slots, 4, 3, FDIM, DDIM);
}